// Round 15
// baseline (622.369 us; speedup 1.0000x reference)
//
#include <hip/hip_runtime.h>
#include <hip/hip_bf16.h>
#include <math.h>

// B=4, S=2048, E=2048, H=16, D=128. Inputs/outputs FP32; internal bf16 MFMA, f32 acc.

typedef __bf16 bf16_t;
typedef __bf16 bf16x2 __attribute__((ext_vector_type(2)));
typedef __bf16 bf16x4 __attribute__((ext_vector_type(4)));
typedef __bf16 bf16x8 __attribute__((ext_vector_type(8)));
typedef float f32x2 __attribute__((ext_vector_type(2)));
typedef float f32x4 __attribute__((ext_vector_type(4)));
typedef float f32x16 __attribute__((ext_vector_type(16)));
typedef unsigned int u32;
typedef u32 u32x4 __attribute__((ext_vector_type(4)));

typedef __attribute__((address_space(1))) const void gas_cvoid;
typedef __attribute__((address_space(3))) void las_void;

#define MFMA16(a, b, c) __builtin_amdgcn_mfma_f32_16x16x32_bf16((a), (b), (c), 0, 0, 0)
#define MFMA32(a, b, c) __builtin_amdgcn_mfma_f32_32x32x16_bf16((a), (b), (c), 0, 0, 0)

__device__ __forceinline__ void gload16(const void* g, void* l) {
  __builtin_amdgcn_global_load_lds((gas_cvoid*)g, (las_void*)l, 16, 0, 0);
}
// lane[i] <-> lane[i+32] pairwise exchange of two regs (T12 primitive, m255)
__device__ __forceinline__ void pl32(u32& a, u32& b) {
  asm volatile("v_permlane32_swap_b32 %0, %1" : "+v"(a), "+v"(b));
}
// bare v_exp_f32 (D = 2^S0); exp2f() is OCML w/ fixup, __exp2f doesn't exist.
__device__ __forceinline__ float fexp2(float x) {
  float r;
  asm("v_exp_f32 %0, %1" : "=v"(r) : "v"(x));
  return r;
}

// ---------------------------------------------------------------------------
// f32 -> bf16: x (blocks 0..16383) + 4 weight matrices (16384..32767), one launch.
// ---------------------------------------------------------------------------
__global__ __launch_bounds__(256) void cvt_all(const float* __restrict__ x,
                                               const float* __restrict__ w0,
                                               const float* __restrict__ w1,
                                               const float* __restrict__ w2,
                                               const float* __restrict__ w3,
                                               bf16_t* __restrict__ xo,
                                               bf16_t* __restrict__ o0,
                                               bf16_t* __restrict__ o1,
                                               bf16_t* __restrict__ o2,
                                               bf16_t* __restrict__ o3) {
  const float* in;
  bf16_t* out;
  size_t i;
  if (blockIdx.x < 16384) {
    in = x; out = xo;
    i = ((size_t)blockIdx.x * 256 + threadIdx.x) * 4;
  } else {
    const int which = (blockIdx.x - 16384) >> 12;
    in = which == 0 ? w0 : which == 1 ? w1 : which == 2 ? w2 : w3;
    out = which == 0 ? o0 : which == 1 ? o1 : which == 2 ? o2 : o3;
    i = ((size_t)((blockIdx.x - 16384) & 4095) * 256 + threadIdx.x) * 4;
  }
  f32x4 v = *(const f32x4*)&in[i];
  bf16x4 o;
#pragma unroll
  for (int j = 0; j < 4; ++j) o[j] = (bf16_t)v[j];
  *(bf16x4*)&out[i] = o;
}

// ---------------------------------------------------------------------------
// Fused Q/K/V projection GEMM: grid 768 = 3 segments x 256 blocks (round-14,
// verified; SQ_LDS_BANK_CONFLICT = 0, MfmaUtil ~50%).
// ---------------------------------------------------------------------------
__global__ __launch_bounds__(512, 2) void gemm_qkv(const bf16_t* __restrict__ xb,
                                                   const bf16_t* __restrict__ Wq,
                                                   const bf16_t* __restrict__ Wk,
                                                   const bf16_t* __restrict__ Wv,
                                                   bf16_t* __restrict__ Qo,
                                                   bf16_t* __restrict__ Ko,
                                                   bf16_t* __restrict__ Vo) {
  constexpr int K = 2048;
  __shared__ __attribute__((aligned(16))) char lds[131072];
  const int tid = threadIdx.x;
  const int wave = tid >> 6, lane = tid & 63;
  const int seg = blockIdx.x >> 8;          // 0:Q 1:K 2:V
  const int sbid = blockIdx.x & 255;
  const int swz = (sbid & 7) * 32 + (sbid >> 3);  // bijective XCD swizzle
  const int NT = (seg == 2) ? 32 : 8;
  const int m0 = (swz / NT) * 256, n0 = (swz % NT) * 256;
  const bf16_t* A = (seg == 2) ? Wv : xb;
  const bf16_t* Bt = (seg == 0) ? Wq : (seg == 1) ? Wk : xb;
  bf16_t* C = (seg == 0) ? Qo : (seg == 1) ? Ko : Vo;

  const int srow = tid >> 3;
  const int scol = ((tid & 7) ^ (srow & 7)) * 8;
  const bf16_t* aBase = A + (size_t)(m0 + srow) * K + scol;
  const bf16_t* bBase = Bt + (size_t)(n0 + srow) * K + scol;

  const int wm = wave >> 2, wn = wave & 3;
  const int l15 = lane & 15, l4 = lane >> 4;
  const int axor = l15 & 7;
  char* const wdst = lds + wave * 1024;

  f32x4 acc[8][4] = {};

  gload16(bBase, wdst + 32768);
  gload16(bBase + (size_t)64 * K, wdst + 32768 + 8192);
  gload16(bBase + (size_t)128 * K, wdst + 32768 + 16384);
  gload16(bBase + (size_t)192 * K, wdst + 32768 + 24576);
  gload16(aBase, wdst);
  gload16(aBase + (size_t)128 * K, wdst + 16384);
  gload16(aBase + (size_t)64 * K, wdst + 8192);
  gload16(aBase + (size_t)192 * K, wdst + 24576);

  for (int t = 0; t < 32; ++t) {
    const int buf = t & 1, nbuf = buf ^ 1;
    const char* la = lds + buf * 65536 + wm * 16384;
    const char* lb = lds + buf * 65536 + 32768 + (wn >> 1) * 16384 + (wn & 1) * 8192;
    char* const ndst = wdst + nbuf * 65536;
    bf16x8 bF[4][2];
#pragma unroll
    for (int q = 0; q < 4; ++q) {
      if (q == 0) {
        asm volatile("s_waitcnt vmcnt(2)" ::: "memory");
      } else if (q == 2) {
        if (t < 31)
          asm volatile("s_waitcnt vmcnt(4)" ::: "memory");
        else
          asm volatile("s_waitcnt vmcnt(0)" ::: "memory");
      }
      __builtin_amdgcn_s_barrier();

      bf16x8 aF[2][2];
#pragma unroll
      for (int dm = 0; dm < 2; ++dm)
#pragma unroll
        for (int kk = 0; kk < 2; ++kk)
          aF[dm][kk] = *(const bf16x8*)(la + ((q * 2 + dm) * 16 + l15) * 128 +
                                        ((kk * 4 + l4) ^ axor) * 16);
      if (q == 0) {
#pragma unroll
        for (int ni = 0; ni < 4; ++ni)
#pragma unroll
          for (int kk = 0; kk < 2; ++kk)
            bF[ni][kk] = *(const bf16x8*)(lb + (ni * 16 + l15) * 128 +
                                          ((kk * 4 + l4) ^ axor) * 16);
      }
      if (t < 31) {
        const int off = (t + 1) * 64;
        if (q == 0) {
          gload16(bBase + off, ndst + 32768);
          gload16(bBase + (size_t)64 * K + off, ndst + 32768 + 8192);
        } else if (q == 1) {
          gload16(bBase + (size_t)128 * K + off, ndst + 32768 + 16384);
          gload16(bBase + (size_t)192 * K + off, ndst + 32768 + 24576);
        } else if (q == 2) {
          gload16(aBase + off, ndst);
          gload16(aBase + (size_t)128 * K + off, ndst + 16384);
        } else {
          gload16(aBase + (size_t)64 * K + off, ndst + 8192);
          gload16(aBase + (size_t)192 * K + off, ndst + 24576);
        }
      }
      __builtin_amdgcn_s_setprio(1);
#pragma unroll
      for (int kk = 0; kk < 2; ++kk)
#pragma unroll
        for (int dm = 0; dm < 2; ++dm)
#pragma unroll
          for (int ni = 0; ni < 4; ++ni)
            acc[q * 2 + dm][ni] = MFMA16(aF[dm][kk], bF[ni][kk], acc[q * 2 + dm][ni]);
      __builtin_amdgcn_s_setprio(0);
    }
  }

  const int rBase = m0 + wm * 128 + l4 * 4;
  const int cBase = n0 + wn * 64 + l15;
#pragma unroll
  for (int mi = 0; mi < 8; ++mi)
#pragma unroll
    for (int ni = 0; ni < 4; ++ni)
#pragma unroll
      for (int j = 0; j < 4; ++j) {
        const int r = rBase + mi * 16 + j;
        const int c = cBase + ni * 16;
        const bf16_t v = (bf16_t)acc[mi][ni][j];
        if (seg < 2) {  // Q/K: r = b*2048+s, c = h*128+d
          const int b = r >> 11, s = r & 2047, hh = c >> 7, d = c & 127;
          C[(((size_t)(b * 16 + hh)) * 2048 + s) * 128 + d] = v;
        } else {  // V^T: r = h*128+dd (Wv row), c = b*2048+s
          const int hh = r >> 7, dd = r & 127, b = c >> 11, s = c & 2047;
          C[((size_t)(b * 16 + hh) * 128 + dd) * 2048 + s] = v;
        }
      }
}

// ---------------------------------------------------------------------------
// Final output GEMM (verified): d_out[M][2048] f32.
// ---------------------------------------------------------------------------
__global__ __launch_bounds__(512, 2) void gemm_out(const bf16_t* __restrict__ A,
                                                   const bf16_t* __restrict__ Bt,
                                                   float* __restrict__ C) {
  constexpr int K = 2048;
  __shared__ __attribute__((aligned(16))) char lds[131072];
  const int tid = threadIdx.x;
  const int wave = tid >> 6, lane = tid & 63;
  const int bid = blockIdx.x;
  const int swz = (bid & 7) * 32 + (bid >> 3);
  const int m0 = (swz / 8) * 256, n0 = (swz % 8) * 256;

  const int srow = tid >> 3;
  const int scol = ((tid & 7) ^ (srow & 7)) * 8;
  const bf16_t* aBase = A + (size_t)(m0 + srow) * K + scol;
  const bf16_t* bBase = Bt + (size_t)(n0 + srow) * K + scol;

  const int wm = wave >> 2, wn = wave & 3;
  const int l15 = lane & 15, l4 = lane >> 4;
  const int axor = l15 & 7;
  char* const wdst = lds + wave * 1024;

  f32x4 acc[8][4] = {};

  gload16(bBase, wdst + 32768);
  gload16(bBase + (size_t)64 * K, wdst + 32768 + 8192);
  gload16(bBase + (size_t)128 * K, wdst + 32768 + 16384);
  gload16(bBase + (size_t)192 * K, wdst + 32768 + 24576);
  gload16(aBase, wdst);
  gload16(aBase + (size_t)128 * K, wdst + 16384);
  gload16(aBase + (size_t)64 * K, wdst + 8192);
  gload16(aBase + (size_t)192 * K, wdst + 24576);

  for (int t = 0; t < 32; ++t) {
    const int buf = t & 1, nbuf = buf ^ 1;
    const char* la = lds + buf * 65536 + wm * 16384;
    const char* lb = lds + buf * 65536 + 32768 + (wn >> 1) * 16384 + (wn & 1) * 8192;
    char* const ndst = wdst + nbuf * 65536;
    bf16x8 bF[4][2];
#pragma unroll
    for (int q = 0; q < 4; ++q) {
      if (q == 0) {
        asm volatile("s_waitcnt vmcnt(2)" ::: "memory");
      } else if (q == 2) {
        if (t < 31)
          asm volatile("s_waitcnt vmcnt(4)" ::: "memory");
        else
          asm volatile("s_waitcnt vmcnt(0)" ::: "memory");
      }
      __builtin_amdgcn_s_barrier();

      bf16x8 aF[2][2];
#pragma unroll
      for (int dm = 0; dm < 2; ++dm)
#pragma unroll
        for (int kk = 0; kk < 2; ++kk)
          aF[dm][kk] = *(const bf16x8*)(la + ((q * 2 + dm) * 16 + l15) * 128 +
                                        ((kk * 4 + l4) ^ axor) * 16);
      if (q == 0) {
#pragma unroll
        for (int ni = 0; ni < 4; ++ni)
#pragma unroll
          for (int kk = 0; kk < 2; ++kk)
            bF[ni][kk] = *(const bf16x8*)(lb + (ni * 16 + l15) * 128 +
                                          ((kk * 4 + l4) ^ axor) * 16);
      }
      if (t < 31) {
        const int off = (t + 1) * 64;
        if (q == 0) {
          gload16(bBase + off, ndst + 32768);
          gload16(bBase + (size_t)64 * K + off, ndst + 32768 + 8192);
        } else if (q == 1) {
          gload16(bBase + (size_t)128 * K + off, ndst + 32768 + 16384);
          gload16(bBase + (size_t)192 * K + off, ndst + 32768 + 24576);
        } else if (q == 2) {
          gload16(aBase + off, ndst);
          gload16(aBase + (size_t)128 * K + off, ndst + 16384);
        } else {
          gload16(aBase + (size_t)64 * K + off, ndst + 8192);
          gload16(aBase + (size_t)192 * K + off, ndst + 24576);
        }
      }
      __builtin_amdgcn_s_setprio(1);
#pragma unroll
      for (int kk = 0; kk < 2; ++kk)
#pragma unroll
        for (int dm = 0; dm < 2; ++dm)
#pragma unroll
          for (int ni = 0; ni < 4; ++ni)
            acc[q * 2 + dm][ni] = MFMA16(aF[dm][kk], bF[ni][kk], acc[q * 2 + dm][ni]);
      __builtin_amdgcn_s_setprio(0);
    }
  }

  const int rBase = m0 + wm * 128 + l4 * 4;
  const int cBase = n0 + wn * 64 + l15;
#pragma unroll
  for (int mi = 0; mi < 8; ++mi)
#pragma unroll
    for (int ni = 0; ni < 4; ++ni)
#pragma unroll
      for (int j = 0; j < 4; ++j)
        C[(size_t)(rBase + mi * 16 + j) * 2048 + cBase + ni * 16] = acc[mi][ni][j];
}

// ---------------------------------------------------------------------------
// Fused RoPE + RMSNorm on BOTH Q and K in one dispatch (grid 8192).
// ---------------------------------------------------------------------------
__global__ __launch_bounds__(256) void rope_rms2(bf16_t* __restrict__ Qb,
                                                 bf16_t* __restrict__ Kb,
                                                 const float* __restrict__ Cs,
                                                 const float* __restrict__ Sn) {
  bf16_t* T = (blockIdx.x >> 12) ? Kb : Qb;
  const int bid = blockIdx.x & 4095;
  const int wave = threadIdx.x >> 6, lane = threadIdx.x & 63;
#pragma unroll 1
  for (int rr = 0; rr < 8; ++rr) {
    const size_t row = (size_t)bid * 32 + wave * 8 + rr;
    const int s = (int)(row & 2047);
    bf16_t* p = &T[row * 128 + 2 * lane];
    const float a0 = (float)p[0], a1 = (float)p[1];
    f32x2 cv = *(const f32x2*)&Cs[(size_t)s * 128 + 2 * lane];
    f32x2 sv = *(const f32x2*)&Sn[(size_t)s * 128 + 2 * lane];
    const float p0 = __shfl_xor(a0, 32);
    const float p1 = __shfl_xor(a1, 32);
    const float sg = (lane < 32) ? -1.f : 1.f;
    const float r0 = a0 * cv.x + sg * p0 * sv.x;
    const float r1 = a1 * cv.y + sg * p1 * sv.y;
    float ss = r0 * r0 + r1 * r1;
#pragma unroll
    for (int off = 1; off < 64; off <<= 1) ss += __shfl_xor(ss, off);
    const float inv = rsqrtf(ss * (1.0f / 128.0f) + 1e-6f);
    p[0] = (bf16_t)(r0 * inv);
    p[1] = (bf16_t)(r1 * inv);
  }
}

// ---------------------------------------------------------------------------
// Flash attention, 2 SEQUENTIAL q-tiles per wave (register-safe round-10
// redo). Grid 256: 64 bh x 4 qb of 512 q-rows; wave owns rows q0..q0+31 (A)
// and q0+256..q0+287 (B). Per kt: full A {QK,SM,PV}, sched_barrier(0), full
// B {QK,SM,PV} -- sa/w registers REUSED across tiles (round 10's spill came
// from interleaving; sequential peaks ~260 unified regs, no spill). Gains:
// barrier/rotation overhead per q-row halves; K/V HBM refetch ~halves.
// Static-bound softmax + counted-vmcnt rotation + r&7 swizzle (verified).
// ---------------------------------------------------------------------------
__global__ __launch_bounds__(512, 2) void attn_fwd(const bf16_t* __restrict__ Q,
                                                   const bf16_t* __restrict__ K,
                                                   const bf16_t* __restrict__ Vt,
                                                   bf16_t* __restrict__ Y) {
  __shared__ __attribute__((aligned(16))) bf16_t ldsK[2][64 * 128];
  __shared__ __attribute__((aligned(16))) bf16_t ldsV[2][128 * 64];
  const int tid = threadIdx.x, wave = tid >> 6, lane = tid & 63;
  const int l31 = lane & 31, hi = lane >> 5;
  const int pid = blockIdx.x;
  const int bh = (pid & 7) * 8 + ((pid >> 3) & 7);
  const int qb = pid >> 6;  // 0..3
  const int b = bh >> 4, h = bh & 15;
  const bf16_t* Qh = Q + (size_t)bh * 2048 * 128;
  const bf16_t* Kh = K + (size_t)bh * 2048 * 128;
  const bf16_t* Vh = Vt + (size_t)bh * 128 * 2048;
  const int q0 = qb * 512 + wave * 32;  // tile A; tile B = q0 + 256

  bf16x8 qfA[8], qfB[8];
#pragma unroll
  for (int dk = 0; dk < 8; ++dk) {
    qfA[dk] = *(const bf16x8*)&Qh[(size_t)(q0 + l31) * 128 + dk * 16 + hi * 8];
    qfB[dk] = *(const bf16x8*)&Qh[(size_t)(q0 + 256 + l31) * 128 + dk * 16 + hi * 8];
  }

  f32x16 otA[4] = {}, otB[4] = {};
  float lA = 0.f, lB = 0.f;
  const float SC2 = 0.08838834764831845f * 1.44269504088896341f;  // scale*log2e
  const float NC2 = -11.5f * 1.44269504088896341f;                // -M*log2e

  auto stage = [&](int kt, int bu) {
#pragma unroll
    for (int i = 0; i < 2; ++i) {
      const int G = wave * 64 + lane + i * 512;
      char* dstK = (char*)&ldsK[bu][0] + (wave * 64 + i * 512) * 16;
      char* dstV = (char*)&ldsV[bu][0] + (wave * 64 + i * 512) * 16;
      const int kvr = G >> 4, glk = G & 15;
      gload16(Kh + (size_t)(kt * 64 + kvr) * 128 + ((glk ^ (kvr & 7)) * 8), dstK);
      const int dr = G >> 3, glv = G & 7;
      gload16(Vh + (size_t)dr * 2048 + kt * 64 + ((glv ^ (dr & 7)) * 8), dstV);
    }
  };

  // one q-tile's full {QK, SM, PV} against K/V tile in buf bu.
  // sa/w are locals -> register-reused between the A and B invocations.
  auto tile_work = [&](const bf16x8 (&qf)[8], f32x16 (&ot)[4], float& lr,
                       int bu, int r7) {
    f32x16 sa0 = {}, sa1 = {};
    __builtin_amdgcn_s_setprio(1);
#pragma unroll
    for (int dk = 0; dk < 8; ++dk) {
      const int g = ((dk << 1) | hi) ^ r7;
      bf16x8 kf0 = *(const bf16x8*)&ldsK[bu][l31 * 128 + g * 8];
      bf16x8 kf1 = *(const bf16x8*)&ldsK[bu][(32 + l31) * 128 + g * 8];
      sa0 = MFMA32(kf0, qf[dk], sa0);
      sa1 = MFMA32(kf1, qf[dk], sa1);
    }
    __builtin_amdgcn_s_setprio(0);

    u32 w[2][8];
    float ssum = 0.f;
#pragma unroll
    for (int i = 0; i < 8; ++i) {
      const float p0 = fexp2(fmaf(sa0[2 * i], SC2, NC2));
      const float p1 = fexp2(fmaf(sa0[2 * i + 1], SC2, NC2));
      const float p2 = fexp2(fmaf(sa1[2 * i], SC2, NC2));
      const float p3 = fexp2(fmaf(sa1[2 * i + 1], SC2, NC2));
      ssum += (p0 + p1) + (p2 + p3);
      bf16x2 t0, t1;
      t0[0] = (bf16_t)p0; t0[1] = (bf16_t)p1;
      t1[0] = (bf16_t)p2; t1[1] = (bf16_t)p3;
      w[0][i] = __builtin_bit_cast(u32, t0);
      w[1][i] = __builtin_bit_cast(u32, t1);
    }
    ssum += __shfl_xor(ssum, 32);
    lr += ssum;

#pragma unroll
    for (int ks = 0; ks < 4; ++ks) {
      const int tsel = ks >> 1, k4 = (ks & 1) * 4;
      u32 a0 = w[tsel][k4 + 0], b0 = w[tsel][k4 + 2];
      u32 a1 = w[tsel][k4 + 1], b1 = w[tsel][k4 + 3];
      pl32(a0, b0);
      pl32(a1, b1);
      u32x4 fw;
      fw.x = a0; fw.y = a1; fw.z = b0; fw.w = b1;
      const bf16x8 pf = __builtin_bit_cast(bf16x8, fw);
      const int gv = ((ks << 1) | hi) ^ r7;
      __builtin_amdgcn_s_setprio(1);
#pragma unroll
      for (int db = 0; db < 4; ++db) {
        bf16x8 vf = *(const bf16x8*)&ldsV[bu][(db * 32 + l31) * 64 + gv * 8];
        ot[db] = MFMA32(vf, pf, ot[db]);
      }
      __builtin_amdgcn_s_setprio(0);
    }
  };

  // prologue: tiles 0 and 1 in flight; wait tile 0 only
  stage(0, 0);
  stage(1, 1);
  asm volatile("s_waitcnt vmcnt(4)" ::: "memory");
  __builtin_amdgcn_s_barrier();
  __builtin_amdgcn_sched_barrier(0);

  for (int kt = 0; kt < 32; ++kt) {
    const int bu = kt & 1;
    const int r7 = l31 & 7;

    tile_work(qfA, otA, lA, bu, r7);
    __builtin_amdgcn_sched_barrier(0);  // pin: keep A and B sections sequential
    tile_work(qfB, otB, lB, bu, r7);

    // ---- counted-vmcnt buffer rotation (never drain to 0 mid-loop)
    __builtin_amdgcn_s_barrier();
    __builtin_amdgcn_sched_barrier(0);
    if (kt < 30) {
      stage(kt + 2, bu);
      asm volatile("s_waitcnt vmcnt(4)" ::: "memory");
    } else {
      asm volatile("s_waitcnt vmcnt(0)" ::: "memory");
    }
    __builtin_amdgcn_s_barrier();
    __builtin_amdgcn_sched_barrier(0);
  }

  // ---- epilogue, both tiles
  const float rlA = 1.f / lA, rlB = 1.f / lB;
  const size_t yrA = ((size_t)(b * 2048 + q0 + l31) * 16 + h) * 128;
  const size_t yrB = ((size_t)(b * 2048 + q0 + 256 + l31) * 16 + h) * 128;
#pragma unroll
  for (int db = 0; db < 4; ++db)
#pragma unroll
    for (int g2 = 0; g2 < 4; ++g2) {
      bf16x4 ovA, ovB;
#pragma unroll
      for (int j = 0; j < 4; ++j) {
        ovA[j] = (bf16_t)(otA[db][g2 * 4 + j] * rlA);
        ovB[j] = (bf16_t)(otB[db][g2 * 4 + j] * rlB);
      }
      *(bf16x4*)&Y[yrA + db * 32 + g2 * 8 + hi * 4] = ovA;
      *(bf16x4*)&Y[yrB + db * 32 + g2 * 8 + hi * 4] = ovB;
    }
}

// ---------------------------------------------------------------------------
extern "C" void kernel_launch(void* const* d_in, const int* in_sizes, int n_in,
                              void* d_out, int out_size, void* d_ws, size_t ws_size,
                              hipStream_t stream) {
  const float* x = (const float*)d_in[0];
  const float* cs = (const float*)d_in[1];
  const float* sn = (const float*)d_in[2];
  const float* Wq = (const float*)d_in[3];
  const float* Wk = (const float*)d_in[4];
  const float* Wv = (const float*)d_in[5];
  const float* Wo = (const float*)d_in[6];

  bf16_t* ws = (bf16_t*)d_ws;
  const size_t TSZ = (size_t)4 * 2048 * 2048;
  const size_t WSZ = (size_t)2048 * 2048;
  bf16_t* xb = ws;
  bf16_t* Wqb = ws + TSZ;
  bf16_t* Wkb = Wqb + WSZ;
  bf16_t* Wvb = Wkb + WSZ;
  bf16_t* Wob = Wvb + WSZ;
  bf16_t* Qb = ws + 2 * TSZ;
  bf16_t* Kb = Qb + TSZ;
  bf16_t* Vtb = Kb + TSZ;
  bf16_t* Yb = xb;

  cvt_all<<<32768, 256, 0, stream>>>(x, Wq, Wk, Wv, Wo, xb, Wqb, Wkb, Wvb, Wob);
  gemm_qkv<<<768, 512, 0, stream>>>(xb, Wqb, Wkb, Wvb, Qb, Kb, Vtb);
  rope_rms2<<<8192, 256, 0, stream>>>(Qb, Kb, cs, sn);
  attn_fwd<<<256, 512, 0, stream>>>(Qb, Kb, Vtb, Yb);
  gemm_out<<<256, 512, 0, stream>>>(Yb, Wob, (float*)d_out);
}

// Round 16
// 470.132 us; speedup vs baseline: 1.3238x; 1.3238x over previous
//
#include <hip/hip_runtime.h>
#include <hip/hip_bf16.h>
#include <math.h>

// B=4, S=2048, E=2048, H=16, D=128. Inputs/outputs FP32; internal bf16 MFMA, f32 acc.
// FINAL (round-14 verified config, 471.6 us):
//   cvt_all -> gemm_qkv (fused Q/K/V^T projections) -> rope_rms2 -> attn_fwd
//   (static-bound softmax) -> gemm_out.

typedef __bf16 bf16_t;
typedef __bf16 bf16x2 __attribute__((ext_vector_type(2)));
typedef __bf16 bf16x4 __attribute__((ext_vector_type(4)));
typedef __bf16 bf16x8 __attribute__((ext_vector_type(8)));
typedef float f32x2 __attribute__((ext_vector_type(2)));
typedef float f32x4 __attribute__((ext_vector_type(4)));
typedef float f32x16 __attribute__((ext_vector_type(16)));
typedef unsigned int u32;
typedef u32 u32x4 __attribute__((ext_vector_type(4)));

typedef __attribute__((address_space(1))) const void gas_cvoid;
typedef __attribute__((address_space(3))) void las_void;

#define MFMA16(a, b, c) __builtin_amdgcn_mfma_f32_16x16x32_bf16((a), (b), (c), 0, 0, 0)
#define MFMA32(a, b, c) __builtin_amdgcn_mfma_f32_32x32x16_bf16((a), (b), (c), 0, 0, 0)

__device__ __forceinline__ void gload16(const void* g, void* l) {
  __builtin_amdgcn_global_load_lds((gas_cvoid*)g, (las_void*)l, 16, 0, 0);
}
// lane[i] <-> lane[i+32] pairwise exchange of two regs (T12 primitive, m255)
__device__ __forceinline__ void pl32(u32& a, u32& b) {
  asm volatile("v_permlane32_swap_b32 %0, %1" : "+v"(a), "+v"(b));
}
// bare v_exp_f32 (D = 2^S0); exp2f() is OCML w/ fixup, __exp2f doesn't exist.
__device__ __forceinline__ float fexp2(float x) {
  float r;
  asm("v_exp_f32 %0, %1" : "=v"(r) : "v"(x));
  return r;
}

// ---------------------------------------------------------------------------
// f32 -> bf16: x (blocks 0..16383) + 4 weight matrices (16384..32767), one launch.
// ---------------------------------------------------------------------------
__global__ __launch_bounds__(256) void cvt_all(const float* __restrict__ x,
                                               const float* __restrict__ w0,
                                               const float* __restrict__ w1,
                                               const float* __restrict__ w2,
                                               const float* __restrict__ w3,
                                               bf16_t* __restrict__ xo,
                                               bf16_t* __restrict__ o0,
                                               bf16_t* __restrict__ o1,
                                               bf16_t* __restrict__ o2,
                                               bf16_t* __restrict__ o3) {
  const float* in;
  bf16_t* out;
  size_t i;
  if (blockIdx.x < 16384) {
    in = x; out = xo;
    i = ((size_t)blockIdx.x * 256 + threadIdx.x) * 4;
  } else {
    const int which = (blockIdx.x - 16384) >> 12;
    in = which == 0 ? w0 : which == 1 ? w1 : which == 2 ? w2 : w3;
    out = which == 0 ? o0 : which == 1 ? o1 : which == 2 ? o2 : o3;
    i = ((size_t)((blockIdx.x - 16384) & 4095) * 256 + threadIdx.x) * 4;
  }
  f32x4 v = *(const f32x4*)&in[i];
  bf16x4 o;
#pragma unroll
  for (int j = 0; j < 4; ++j) o[j] = (bf16_t)v[j];
  *(bf16x4*)&out[i] = o;
}

// ---------------------------------------------------------------------------
// Fused Q/K/V projection GEMM: grid 768 = 3 segments x 256 blocks.
// seg 0: Q = x @ Wq^T -> scatter [B,H,S,D];  seg 1: same for K;
// seg 2: V^T = Wv @ x^T -> [B*H][128][2048] (operands swapped).
// 8-phase counted-vmcnt K-loop, 16x16x32 MFMA, 256x256 tile, BK=64.
// Verified: SQ_LDS_BANK_CONFLICT = 0, MfmaUtil ~50%.
// ---------------------------------------------------------------------------
__global__ __launch_bounds__(512, 2) void gemm_qkv(const bf16_t* __restrict__ xb,
                                                   const bf16_t* __restrict__ Wq,
                                                   const bf16_t* __restrict__ Wk,
                                                   const bf16_t* __restrict__ Wv,
                                                   bf16_t* __restrict__ Qo,
                                                   bf16_t* __restrict__ Ko,
                                                   bf16_t* __restrict__ Vo) {
  constexpr int K = 2048;
  __shared__ __attribute__((aligned(16))) char lds[131072];
  const int tid = threadIdx.x;
  const int wave = tid >> 6, lane = tid & 63;
  const int seg = blockIdx.x >> 8;          // 0:Q 1:K 2:V
  const int sbid = blockIdx.x & 255;
  const int swz = (sbid & 7) * 32 + (sbid >> 3);  // bijective XCD swizzle
  const int NT = (seg == 2) ? 32 : 8;
  const int m0 = (swz / NT) * 256, n0 = (swz % NT) * 256;
  const bf16_t* A = (seg == 2) ? Wv : xb;
  const bf16_t* Bt = (seg == 0) ? Wq : (seg == 1) ? Wk : xb;
  bf16_t* C = (seg == 0) ? Qo : (seg == 1) ? Ko : Vo;

  const int srow = tid >> 3;
  const int scol = ((tid & 7) ^ (srow & 7)) * 8;
  const bf16_t* aBase = A + (size_t)(m0 + srow) * K + scol;
  const bf16_t* bBase = Bt + (size_t)(n0 + srow) * K + scol;

  const int wm = wave >> 2, wn = wave & 3;
  const int l15 = lane & 15, l4 = lane >> 4;
  const int axor = l15 & 7;
  char* const wdst = lds + wave * 1024;

  f32x4 acc[8][4] = {};

  gload16(bBase, wdst + 32768);
  gload16(bBase + (size_t)64 * K, wdst + 32768 + 8192);
  gload16(bBase + (size_t)128 * K, wdst + 32768 + 16384);
  gload16(bBase + (size_t)192 * K, wdst + 32768 + 24576);
  gload16(aBase, wdst);
  gload16(aBase + (size_t)128 * K, wdst + 16384);
  gload16(aBase + (size_t)64 * K, wdst + 8192);
  gload16(aBase + (size_t)192 * K, wdst + 24576);

  for (int t = 0; t < 32; ++t) {
    const int buf = t & 1, nbuf = buf ^ 1;
    const char* la = lds + buf * 65536 + wm * 16384;
    const char* lb = lds + buf * 65536 + 32768 + (wn >> 1) * 16384 + (wn & 1) * 8192;
    char* const ndst = wdst + nbuf * 65536;
    bf16x8 bF[4][2];
#pragma unroll
    for (int q = 0; q < 4; ++q) {
      if (q == 0) {
        asm volatile("s_waitcnt vmcnt(2)" ::: "memory");
      } else if (q == 2) {
        if (t < 31)
          asm volatile("s_waitcnt vmcnt(4)" ::: "memory");
        else
          asm volatile("s_waitcnt vmcnt(0)" ::: "memory");
      }
      __builtin_amdgcn_s_barrier();

      bf16x8 aF[2][2];
#pragma unroll
      for (int dm = 0; dm < 2; ++dm)
#pragma unroll
        for (int kk = 0; kk < 2; ++kk)
          aF[dm][kk] = *(const bf16x8*)(la + ((q * 2 + dm) * 16 + l15) * 128 +
                                        ((kk * 4 + l4) ^ axor) * 16);
      if (q == 0) {
#pragma unroll
        for (int ni = 0; ni < 4; ++ni)
#pragma unroll
          for (int kk = 0; kk < 2; ++kk)
            bF[ni][kk] = *(const bf16x8*)(lb + (ni * 16 + l15) * 128 +
                                          ((kk * 4 + l4) ^ axor) * 16);
      }
      if (t < 31) {
        const int off = (t + 1) * 64;
        if (q == 0) {
          gload16(bBase + off, ndst + 32768);
          gload16(bBase + (size_t)64 * K + off, ndst + 32768 + 8192);
        } else if (q == 1) {
          gload16(bBase + (size_t)128 * K + off, ndst + 32768 + 16384);
          gload16(bBase + (size_t)192 * K + off, ndst + 32768 + 24576);
        } else if (q == 2) {
          gload16(aBase + off, ndst);
          gload16(aBase + (size_t)128 * K + off, ndst + 16384);
        } else {
          gload16(aBase + (size_t)64 * K + off, ndst + 8192);
          gload16(aBase + (size_t)192 * K + off, ndst + 24576);
        }
      }
      __builtin_amdgcn_s_setprio(1);
#pragma unroll
      for (int kk = 0; kk < 2; ++kk)
#pragma unroll
        for (int dm = 0; dm < 2; ++dm)
#pragma unroll
          for (int ni = 0; ni < 4; ++ni)
            acc[q * 2 + dm][ni] = MFMA16(aF[dm][kk], bF[ni][kk], acc[q * 2 + dm][ni]);
      __builtin_amdgcn_s_setprio(0);
    }
  }

  const int rBase = m0 + wm * 128 + l4 * 4;
  const int cBase = n0 + wn * 64 + l15;
#pragma unroll
  for (int mi = 0; mi < 8; ++mi)
#pragma unroll
    for (int ni = 0; ni < 4; ++ni)
#pragma unroll
      for (int j = 0; j < 4; ++j) {
        const int r = rBase + mi * 16 + j;
        const int c = cBase + ni * 16;
        const bf16_t v = (bf16_t)acc[mi][ni][j];
        if (seg < 2) {  // Q/K: r = b*2048+s, c = h*128+d
          const int b = r >> 11, s = r & 2047, hh = c >> 7, d = c & 127;
          C[(((size_t)(b * 16 + hh)) * 2048 + s) * 128 + d] = v;
        } else {  // V^T: r = h*128+dd (Wv row), c = b*2048+s
          const int hh = r >> 7, dd = r & 127, b = c >> 11, s = c & 2047;
          C[((size_t)(b * 16 + hh) * 128 + dd) * 2048 + s] = v;
        }
      }
}

// ---------------------------------------------------------------------------
// Final output GEMM (verified): d_out[M][2048] f32.
// ---------------------------------------------------------------------------
__global__ __launch_bounds__(512, 2) void gemm_out(const bf16_t* __restrict__ A,
                                                   const bf16_t* __restrict__ Bt,
                                                   float* __restrict__ C) {
  constexpr int K = 2048;
  __shared__ __attribute__((aligned(16))) char lds[131072];
  const int tid = threadIdx.x;
  const int wave = tid >> 6, lane = tid & 63;
  const int bid = blockIdx.x;
  const int swz = (bid & 7) * 32 + (bid >> 3);
  const int m0 = (swz / 8) * 256, n0 = (swz % 8) * 256;

  const int srow = tid >> 3;
  const int scol = ((tid & 7) ^ (srow & 7)) * 8;
  const bf16_t* aBase = A + (size_t)(m0 + srow) * K + scol;
  const bf16_t* bBase = Bt + (size_t)(n0 + srow) * K + scol;

  const int wm = wave >> 2, wn = wave & 3;
  const int l15 = lane & 15, l4 = lane >> 4;
  const int axor = l15 & 7;
  char* const wdst = lds + wave * 1024;

  f32x4 acc[8][4] = {};

  gload16(bBase, wdst + 32768);
  gload16(bBase + (size_t)64 * K, wdst + 32768 + 8192);
  gload16(bBase + (size_t)128 * K, wdst + 32768 + 16384);
  gload16(bBase + (size_t)192 * K, wdst + 32768 + 24576);
  gload16(aBase, wdst);
  gload16(aBase + (size_t)128 * K, wdst + 16384);
  gload16(aBase + (size_t)64 * K, wdst + 8192);
  gload16(aBase + (size_t)192 * K, wdst + 24576);

  for (int t = 0; t < 32; ++t) {
    const int buf = t & 1, nbuf = buf ^ 1;
    const char* la = lds + buf * 65536 + wm * 16384;
    const char* lb = lds + buf * 65536 + 32768 + (wn >> 1) * 16384 + (wn & 1) * 8192;
    char* const ndst = wdst + nbuf * 65536;
    bf16x8 bF[4][2];
#pragma unroll
    for (int q = 0; q < 4; ++q) {
      if (q == 0) {
        asm volatile("s_waitcnt vmcnt(2)" ::: "memory");
      } else if (q == 2) {
        if (t < 31)
          asm volatile("s_waitcnt vmcnt(4)" ::: "memory");
        else
          asm volatile("s_waitcnt vmcnt(0)" ::: "memory");
      }
      __builtin_amdgcn_s_barrier();

      bf16x8 aF[2][2];
#pragma unroll
      for (int dm = 0; dm < 2; ++dm)
#pragma unroll
        for (int kk = 0; kk < 2; ++kk)
          aF[dm][kk] = *(const bf16x8*)(la + ((q * 2 + dm) * 16 + l15) * 128 +
                                        ((kk * 4 + l4) ^ axor) * 16);
      if (q == 0) {
#pragma unroll
        for (int ni = 0; ni < 4; ++ni)
#pragma unroll
          for (int kk = 0; kk < 2; ++kk)
            bF[ni][kk] = *(const bf16x8*)(lb + (ni * 16 + l15) * 128 +
                                          ((kk * 4 + l4) ^ axor) * 16);
      }
      if (t < 31) {
        const int off = (t + 1) * 64;
        if (q == 0) {
          gload16(bBase + off, ndst + 32768);
          gload16(bBase + (size_t)64 * K + off, ndst + 32768 + 8192);
        } else if (q == 1) {
          gload16(bBase + (size_t)128 * K + off, ndst + 32768 + 16384);
          gload16(bBase + (size_t)192 * K + off, ndst + 32768 + 24576);
        } else if (q == 2) {
          gload16(aBase + off, ndst);
          gload16(aBase + (size_t)128 * K + off, ndst + 16384);
        } else {
          gload16(aBase + (size_t)64 * K + off, ndst + 8192);
          gload16(aBase + (size_t)192 * K + off, ndst + 24576);
        }
      }
      __builtin_amdgcn_s_setprio(1);
#pragma unroll
      for (int kk = 0; kk < 2; ++kk)
#pragma unroll
        for (int dm = 0; dm < 2; ++dm)
#pragma unroll
          for (int ni = 0; ni < 4; ++ni)
            acc[q * 2 + dm][ni] = MFMA16(aF[dm][kk], bF[ni][kk], acc[q * 2 + dm][ni]);
      __builtin_amdgcn_s_setprio(0);
    }
  }

  const int rBase = m0 + wm * 128 + l4 * 4;
  const int cBase = n0 + wn * 64 + l15;
#pragma unroll
  for (int mi = 0; mi < 8; ++mi)
#pragma unroll
    for (int ni = 0; ni < 4; ++ni)
#pragma unroll
      for (int j = 0; j < 4; ++j)
        C[(size_t)(rBase + mi * 16 + j) * 2048 + cBase + ni * 16] = acc[mi][ni][j];
}

// ---------------------------------------------------------------------------
// Fused RoPE + RMSNorm on BOTH Q and K in one dispatch (grid 8192).
// ---------------------------------------------------------------------------
__global__ __launch_bounds__(256) void rope_rms2(bf16_t* __restrict__ Qb,
                                                 bf16_t* __restrict__ Kb,
                                                 const float* __restrict__ Cs,
                                                 const float* __restrict__ Sn) {
  bf16_t* T = (blockIdx.x >> 12) ? Kb : Qb;
  const int bid = blockIdx.x & 4095;
  const int wave = threadIdx.x >> 6, lane = threadIdx.x & 63;
#pragma unroll 1
  for (int rr = 0; rr < 8; ++rr) {
    const size_t row = (size_t)bid * 32 + wave * 8 + rr;
    const int s = (int)(row & 2047);
    bf16_t* p = &T[row * 128 + 2 * lane];
    const float a0 = (float)p[0], a1 = (float)p[1];
    f32x2 cv = *(const f32x2*)&Cs[(size_t)s * 128 + 2 * lane];
    f32x2 sv = *(const f32x2*)&Sn[(size_t)s * 128 + 2 * lane];
    const float p0 = __shfl_xor(a0, 32);
    const float p1 = __shfl_xor(a1, 32);
    const float sg = (lane < 32) ? -1.f : 1.f;
    const float r0 = a0 * cv.x + sg * p0 * sv.x;
    const float r1 = a1 * cv.y + sg * p1 * sv.y;
    float ss = r0 * r0 + r1 * r1;
#pragma unroll
    for (int off = 1; off < 64; off <<= 1) ss += __shfl_xor(ss, off);
    const float inv = rsqrtf(ss * (1.0f / 128.0f) + 1e-6f);
    p[0] = (bf16_t)(r0 * inv);
    p[1] = (bf16_t)(r1 * inv);
  }
}

// ---------------------------------------------------------------------------
// Flash attention (round-9 structure, 178 us verified).
// Static-bound softmax (Cauchy-Schwarz M=11.5 from QK-RMSNorm), counted-vmcnt
// rotation, r&7 swizzle, permlane32 P-exchange, setprio MFMA clusters.
// 2-q-tile variants closed: interleaved (r10) and sequential (r15) both spill
// (~270 unified regs > 256/wave at 2 waves/SIMD).
// ---------------------------------------------------------------------------
__global__ __launch_bounds__(512, 2) void attn_fwd(const bf16_t* __restrict__ Q,
                                                   const bf16_t* __restrict__ K,
                                                   const bf16_t* __restrict__ Vt,
                                                   bf16_t* __restrict__ Y) {
  __shared__ __attribute__((aligned(16))) bf16_t ldsK[2][64 * 128];
  __shared__ __attribute__((aligned(16))) bf16_t ldsV[2][128 * 64];
  const int tid = threadIdx.x, wave = tid >> 6, lane = tid & 63;
  const int l31 = lane & 31, hi = lane >> 5;
  const int pid = blockIdx.x;
  const int bh = (pid & 7) * 8 + ((pid >> 3) & 7);
  const int qb = pid >> 6;
  const int b = bh >> 4, h = bh & 15;
  const bf16_t* Qh = Q + (size_t)bh * 2048 * 128;
  const bf16_t* Kh = K + (size_t)bh * 2048 * 128;
  const bf16_t* Vh = Vt + (size_t)bh * 128 * 2048;
  const int q0 = qb * 256 + wave * 32;

  bf16x8 qf[8];
#pragma unroll
  for (int dk = 0; dk < 8; ++dk)
    qf[dk] = *(const bf16x8*)&Qh[(size_t)(q0 + l31) * 128 + dk * 16 + hi * 8];

  f32x16 ot[4] = {};
  float l_r = 0.f;
  const float SC2 = 0.08838834764831845f * 1.44269504088896341f;  // scale*log2e
  const float NC2 = -11.5f * 1.44269504088896341f;                // -M*log2e

  auto stage = [&](int kt, int bu) {
#pragma unroll
    for (int i = 0; i < 2; ++i) {
      const int G = wave * 64 + lane + i * 512;
      char* dstK = (char*)&ldsK[bu][0] + (wave * 64 + i * 512) * 16;
      char* dstV = (char*)&ldsV[bu][0] + (wave * 64 + i * 512) * 16;
      const int kvr = G >> 4, glk = G & 15;
      gload16(Kh + (size_t)(kt * 64 + kvr) * 128 + ((glk ^ (kvr & 7)) * 8), dstK);
      const int dr = G >> 3, glv = G & 7;
      gload16(Vh + (size_t)dr * 2048 + kt * 64 + ((glv ^ (dr & 7)) * 8), dstV);
    }
  };

  // prologue: tiles 0 and 1 in flight; wait tile 0 only
  stage(0, 0);
  stage(1, 1);
  asm volatile("s_waitcnt vmcnt(4)" ::: "memory");
  __builtin_amdgcn_s_barrier();
  __builtin_amdgcn_sched_barrier(0);

  for (int kt = 0; kt < 32; ++kt) {
    const int bu = kt & 1;
    const int r7 = l31 & 7;

    // ---- S^T = K @ Q^T (two independent 8-deep MFMA chains)
    f32x16 sa0 = {}, sa1 = {};
    __builtin_amdgcn_s_setprio(1);
#pragma unroll
    for (int dk = 0; dk < 8; ++dk) {
      const int g = ((dk << 1) | hi) ^ r7;
      bf16x8 kf0 = *(const bf16x8*)&ldsK[bu][l31 * 128 + g * 8];
      bf16x8 kf1 = *(const bf16x8*)&ldsK[bu][(32 + l31) * 128 + g * 8];
      sa0 = MFMA32(kf0, qf[dk], sa0);
      sa1 = MFMA32(kf1, qf[dk], sa1);
    }
    __builtin_amdgcn_s_setprio(0);

    // ---- static-bound softmax: p = 2^(fma(s,SC2,NC2)); no max/rescale path
    u32 w[2][8];
    float ssum = 0.f;
#pragma unroll
    for (int i = 0; i < 8; ++i) {
      const float p0 = fexp2(fmaf(sa0[2 * i], SC2, NC2));
      const float p1 = fexp2(fmaf(sa0[2 * i + 1], SC2, NC2));
      const float p2 = fexp2(fmaf(sa1[2 * i], SC2, NC2));
      const float p3 = fexp2(fmaf(sa1[2 * i + 1], SC2, NC2));
      ssum += (p0 + p1) + (p2 + p3);
      bf16x2 t0, t1;
      t0[0] = (bf16_t)p0; t0[1] = (bf16_t)p1;
      t1[0] = (bf16_t)p2; t1[1] = (bf16_t)p3;
      w[0][i] = __builtin_bit_cast(u32, t0);
      w[1][i] = __builtin_bit_cast(u32, t1);
    }
    ssum += __shfl_xor(ssum, 32);
    l_r += ssum;

    // ---- O^T += V^T @ P (P frags via permlane32_swap)
#pragma unroll
    for (int ks = 0; ks < 4; ++ks) {
      const int tsel = ks >> 1, k4 = (ks & 1) * 4;
      u32 a0 = w[tsel][k4 + 0], b0 = w[tsel][k4 + 2];
      u32 a1 = w[tsel][k4 + 1], b1 = w[tsel][k4 + 3];
      pl32(a0, b0);
      pl32(a1, b1);
      u32x4 fw;
      fw.x = a0; fw.y = a1; fw.z = b0; fw.w = b1;
      const bf16x8 pf = __builtin_bit_cast(bf16x8, fw);
      const int gv = ((ks << 1) | hi) ^ r7;
      __builtin_amdgcn_s_setprio(1);
#pragma unroll
      for (int db = 0; db < 4; ++db) {
        bf16x8 vf = *(const bf16x8*)&ldsV[bu][(db * 32 + l31) * 64 + gv * 8];
        ot[db] = MFMA32(vf, pf, ot[db]);
      }
      __builtin_amdgcn_s_setprio(0);
    }

    // ---- counted-vmcnt buffer rotation (never drain to 0 mid-loop)
    __builtin_amdgcn_s_barrier();
    __builtin_amdgcn_sched_barrier(0);
    if (kt < 30) {
      stage(kt + 2, bu);
      asm volatile("s_waitcnt vmcnt(4)" ::: "memory");
    } else {
      asm volatile("s_waitcnt vmcnt(0)" ::: "memory");
    }
    __builtin_amdgcn_s_barrier();
    __builtin_amdgcn_sched_barrier(0);
  }

  const float rl = 1.f / l_r;
  const size_t yrow = ((size_t)(b * 2048 + q0 + l31) * 16 + h) * 128;
#pragma unroll
  for (int db = 0; db < 4; ++db)
#pragma unroll
    for (int g2 = 0; g2 < 4; ++g2) {
      bf16x4 ov;
#pragma unroll
      for (int j = 0; j < 4; ++j) ov[j] = (bf16_t)(ot[db][g2 * 4 + j] * rl);
      *(bf16x4*)&Y[yrow + db * 32 + g2 * 8 + hi * 4] = ov;
    }
}

// ---------------------------------------------------------------------------
extern "C" void kernel_launch(void* const* d_in, const int* in_sizes, int n_in,
                              void* d_out, int out_size, void* d_ws, size_t ws_size,
                              hipStream_t stream) {
  const float* x = (const float*)d_in[0];
  const float* cs = (const float*)d_in[1];
  const float* sn = (const float*)d_in[2];
  const float* Wq = (const float*)d_in[3];
  const float* Wk = (const float*)d_in[4];
  const float* Wv = (const float*)d_in[5];
  const float* Wo = (const float*)d_in[6];

  bf16_t* ws = (bf16_t*)d_ws;
  const size_t TSZ = (size_t)4 * 2048 * 2048;
  const size_t WSZ = (size_t)2048 * 2048;
  bf16_t* xb = ws;
  bf16_t* Wqb = ws + TSZ;
  bf16_t* Wkb = Wqb + WSZ;
  bf16_t* Wvb = Wkb + WSZ;
  bf16_t* Wob = Wvb + WSZ;
  bf16_t* Qb = ws + 2 * TSZ;
  bf16_t* Kb = Qb + TSZ;
  bf16_t* Vtb = Kb + TSZ;
  bf16_t* Yb = xb;

  cvt_all<<<32768, 256, 0, stream>>>(x, Wq, Wk, Wv, Wo, xb, Wqb, Wkb, Wvb, Wob);
  gemm_qkv<<<768, 512, 0, stream>>>(xb, Wqb, Wkb, Wvb, Qb, Kb, Vtb);
  rope_rms2<<<8192, 256, 0, stream>>>(Qb, Kb, cs, sn);
  attn_fwd<<<512, 512, 0, stream>>>(Qb, Kb, Vtb, Yb);
  gemm_out<<<256, 512, 0, stream>>>(Yb, Wob, (float*)d_out);
}